// Round 8
// baseline (1741.862 us; speedup 1.0000x reference)
//
#include <hip/hip_runtime.h>
#include <hip/hip_fp16.h>

// LSTM B=256,T=512,IN=64,H=128,L=2 + FC:
//  K0 cvt    : x, w_ih0, w_ih1 -> fp16 (ws)
//  KG (MFMA) : xg0 = x16.Wih0^T + bias   [131072,512] fp16 (ws)
//  KR (L0)   : recurrent (MFMA); writes h0_all fp16
//  KG (MFMA) : xg1 = h0_all.Wih1^T + bias
//  KR (L1)   : recurrent (MFMA) + fused FC -> out
//
// KR round-8: MFMA recurrence. 16 blocks x 512 thr (8 waves); block owns 16
// batch elements. Per step: gates^T[512,16] = W_hh.h^T via 16x16x32 f16 MFMA.
// Wave w does m-tiles {w,w+8,w+16,w+24} (i,f,g,o of units 16w..16w+15);
// A-frags (W_hh fp16) preloaded once = 64 VGPRs (budget 256 @ 2 waves/EU).
// D layout (col=batch, row=4q+reg) puts all 4 gates of a unit on ONE lane ->
// activations non-redundant (4 units/lane), c in regs, h -> ds_write_b64,
// ONE barrier/step. h LDS rows padded to 136 fp16 (2-way banks = free).
// xg: 4x8B loads/lane/step, 2-step prefetch. Wall time = block latency;
// 16/256 CU utilization is intentional (latency-bound recurrence).

#define TT 512
#define MM (256 * 512)

typedef _Float16 f16x2 __attribute__((ext_vector_type(2)));
typedef _Float16 f16x4 __attribute__((ext_vector_type(4)));
typedef _Float16 f16x8 __attribute__((ext_vector_type(8)));
typedef float f32x4 __attribute__((ext_vector_type(4)));

__device__ __forceinline__ float sigmoid_f(float x) {
    float e = __expf(-x);
    return __builtin_amdgcn_rcpf(1.f + e);
}
__device__ __forceinline__ float tanh_f(float x) {
    float e = __expf(2.0f * x);
    return 1.0f - 2.0f * __builtin_amdgcn_rcpf(e + 1.0f);
}

// ---------------- K0: fp32 -> fp16 cvt (vector4) ----------------
__global__ void cvt_f32_f16(const float* __restrict__ src,
                            _Float16* __restrict__ dst, int n4) {
    int i = blockIdx.x * blockDim.x + threadIdx.x;
    int stride = gridDim.x * blockDim.x;
    for (; i < n4; i += stride) {
        float4 v = ((const float4*)src)[i];
        f16x2 a; a.x = (_Float16)v.x; a.y = (_Float16)v.y;
        f16x2 b; b.x = (_Float16)v.z; b.y = (_Float16)v.w;
        ((f16x2*)dst)[2 * i]     = a;
        ((f16x2*)dst)[2 * i + 1] = b;
    }
}

// ---------------- KG: xg[M,512] = A[M,K] . W[512,K]^T + (bih+bhh) ----------
__global__ __launch_bounds__(256, 1) void gemm_xg(
    const _Float16* __restrict__ A, const _Float16* __restrict__ W,
    const float* __restrict__ bih, const float* __restrict__ bhh,
    _Float16* __restrict__ out, int K)
{
    const int l  = threadIdx.x & 63;
    const int w  = threadIdx.x >> 6;
    const int mb = blockIdx.x * 64 + w * 16;
    const int c  = l & 15;
    const int q  = l >> 4;

    __shared__ float biasl[512];
    for (int i = threadIdx.x; i < 512; i += 256) biasl[i] = bih[i] + bhh[i];
    __syncthreads();

    f32x4 C[32];
    #pragma unroll
    for (int i = 0; i < 32; ++i) C[i] = (f32x4){0.f, 0.f, 0.f, 0.f};

    const int nks = K >> 5;
    for (int ks = 0; ks < nks; ++ks) {
        f16x8 Af = *(const f16x8*)(A + (size_t)(mb + c) * K + ks * 32 + q * 8);
        #pragma unroll
        for (int nt = 0; nt < 32; ++nt) {
            f16x8 Bf = *(const f16x8*)(W + (size_t)(nt * 16 + c) * K + ks * 32 + q * 8);
            C[nt] = __builtin_amdgcn_mfma_f32_16x16x32_f16(Af, Bf, C[nt], 0, 0, 0);
        }
    }
    #pragma unroll
    for (int nt = 0; nt < 32; ++nt) {
        float bv = biasl[nt * 16 + c];
        #pragma unroll
        for (int i = 0; i < 4; ++i) {
            int row = mb + q * 4 + i;
            out[(size_t)row * 512 + nt * 16 + c] = (_Float16)(C[nt][i] + bv);
        }
    }
}

// ---------------- KR: recurrent layer via MFMA ----------------
// flags bit0: write h_out (layer0); bit1: final-step FC -> out (layer1)
__global__ __launch_bounds__(512, 2) void lstm_rec_mfma(
    const float* __restrict__ whh,      // [512,128] fp32
    const _Float16* __restrict__ xg,    // [B*T,512] fp16 (bias included)
    _Float16* __restrict__ h_out,       // [B*T,128] fp16
    const float* __restrict__ fc_w, const float* __restrict__ fc_b,
    float* __restrict__ out, int flags)
{
    const int tid = threadIdx.x;
    const int w   = tid >> 6;        // wave 0..7 -> units [16w,16w+16)
    const int l   = tid & 63;
    const int col = l & 15;          // batch within block / D column
    const int q   = l >> 4;          // quad
    const int b0  = blockIdx.x * 16;

    __shared__ __align__(16) _Float16 hb[2][16][136];  // padded rows (2-way banks)
    __shared__ float fcred[16][32];

    // ---- preload A-frags: W_hh rows as fp16, 4 gates x 4 k-chunks = 64 VGPR
    f16x8 af[4][4];
    #pragma unroll
    for (int g = 0; g < 4; ++g) {
        const float* rp = whh + (size_t)(g * 128 + w * 16 + col) * 128;
        #pragma unroll
        for (int ks = 0; ks < 4; ++ks) {
            const float4* p = (const float4*)(rp + ks * 32 + q * 8);
            float4 v0 = p[0], v1 = p[1];
            f16x8 t;
            t[0] = (_Float16)v0.x; t[1] = (_Float16)v0.y;
            t[2] = (_Float16)v0.z; t[3] = (_Float16)v0.w;
            t[4] = (_Float16)v1.x; t[5] = (_Float16)v1.y;
            t[6] = (_Float16)v1.z; t[7] = (_Float16)v1.w;
            af[g][ks] = t;
        }
    }
    for (int i = tid; i < 2 * 16 * 136; i += 512)
        ((_Float16*)hb)[i] = (_Float16)0.f;
    __syncthreads();

    float cr0 = 0.f, cr1 = 0.f, cr2 = 0.f, cr3 = 0.f;

    // xg base for this lane: row (b0+col)*T, element w*16+q*4 (+ g*128)
    const _Float16* xbase = xg + ((size_t)(b0 + col) * TT) * 512 + w * 16 + q * 4;
    f16x4 xc0 = *(const f16x4*)(xbase + 0 * 128);
    f16x4 xc1 = *(const f16x4*)(xbase + 1 * 128);
    f16x4 xc2 = *(const f16x4*)(xbase + 2 * 128);
    f16x4 xc3 = *(const f16x4*)(xbase + 3 * 128);
    f16x4 xn0 = *(const f16x4*)(xbase + 512 + 0 * 128);
    f16x4 xn1 = *(const f16x4*)(xbase + 512 + 1 * 128);
    f16x4 xn2 = *(const f16x4*)(xbase + 512 + 2 * 128);
    f16x4 xn3 = *(const f16x4*)(xbase + 512 + 3 * 128);

    #pragma unroll 1
    for (int step = 0; step < TT; ++step) {
        // prefetch xg(t+2) (clamped; garbage values unused at tail)
        const _Float16* pfp =
            xbase + (size_t)((step + 2 < TT) ? step + 2 : TT - 1) * 512;
        f16x4 xf0 = *(const f16x4*)(pfp + 0 * 128);
        f16x4 xf1 = *(const f16x4*)(pfp + 1 * 128);
        f16x4 xf2 = *(const f16x4*)(pfp + 2 * 128);
        f16x4 xf3 = *(const f16x4*)(pfp + 3 * 128);

        // B-frags: h[col][k] 8 contiguous fp16 per k-chunk
        const _Float16* hrow = &hb[step & 1][col][q * 8];
        f16x8 bf0 = *(const f16x8*)(hrow);
        f16x8 bf1 = *(const f16x8*)(hrow + 32);
        f16x8 bf2 = *(const f16x8*)(hrow + 64);
        f16x8 bf3 = *(const f16x8*)(hrow + 96);

        f32x4 a0 = (f32x4){0.f, 0.f, 0.f, 0.f};
        f32x4 a1 = a0, a2 = a0, a3 = a0;
        a0 = __builtin_amdgcn_mfma_f32_16x16x32_f16(af[0][0], bf0, a0, 0, 0, 0);
        a1 = __builtin_amdgcn_mfma_f32_16x16x32_f16(af[1][0], bf0, a1, 0, 0, 0);
        a2 = __builtin_amdgcn_mfma_f32_16x16x32_f16(af[2][0], bf0, a2, 0, 0, 0);
        a3 = __builtin_amdgcn_mfma_f32_16x16x32_f16(af[3][0], bf0, a3, 0, 0, 0);
        a0 = __builtin_amdgcn_mfma_f32_16x16x32_f16(af[0][1], bf1, a0, 0, 0, 0);
        a1 = __builtin_amdgcn_mfma_f32_16x16x32_f16(af[1][1], bf1, a1, 0, 0, 0);
        a2 = __builtin_amdgcn_mfma_f32_16x16x32_f16(af[2][1], bf1, a2, 0, 0, 0);
        a3 = __builtin_amdgcn_mfma_f32_16x16x32_f16(af[3][1], bf1, a3, 0, 0, 0);
        a0 = __builtin_amdgcn_mfma_f32_16x16x32_f16(af[0][2], bf2, a0, 0, 0, 0);
        a1 = __builtin_amdgcn_mfma_f32_16x16x32_f16(af[1][2], bf2, a1, 0, 0, 0);
        a2 = __builtin_amdgcn_mfma_f32_16x16x32_f16(af[2][2], bf2, a2, 0, 0, 0);
        a3 = __builtin_amdgcn_mfma_f32_16x16x32_f16(af[3][2], bf2, a3, 0, 0, 0);
        a0 = __builtin_amdgcn_mfma_f32_16x16x32_f16(af[0][3], bf3, a0, 0, 0, 0);
        a1 = __builtin_amdgcn_mfma_f32_16x16x32_f16(af[1][3], bf3, a1, 0, 0, 0);
        a2 = __builtin_amdgcn_mfma_f32_16x16x32_f16(af[2][3], bf3, a2, 0, 0, 0);
        a3 = __builtin_amdgcn_mfma_f32_16x16x32_f16(af[3][3], bf3, a3, 0, 0, 0);

        // activations + state update: 4 (unit,batch) pairs per lane, reg r
        f16x4 hp;
        float hh0, hh1, hh2, hh3;
        {
            float iv = sigmoid_f(a0[0] + (float)xc0[0]);
            float fv = sigmoid_f(a1[0] + (float)xc1[0]);
            float gv = tanh_f  (a2[0] + (float)xc2[0]);
            float ov = sigmoid_f(a3[0] + (float)xc3[0]);
            cr0 = fv * cr0 + iv * gv; hh0 = ov * tanh_f(cr0);
        }
        {
            float iv = sigmoid_f(a0[1] + (float)xc0[1]);
            float fv = sigmoid_f(a1[1] + (float)xc1[1]);
            float gv = tanh_f  (a2[1] + (float)xc2[1]);
            float ov = sigmoid_f(a3[1] + (float)xc3[1]);
            cr1 = fv * cr1 + iv * gv; hh1 = ov * tanh_f(cr1);
        }
        {
            float iv = sigmoid_f(a0[2] + (float)xc0[2]);
            float fv = sigmoid_f(a1[2] + (float)xc1[2]);
            float gv = tanh_f  (a2[2] + (float)xc2[2]);
            float ov = sigmoid_f(a3[2] + (float)xc3[2]);
            cr2 = fv * cr2 + iv * gv; hh2 = ov * tanh_f(cr2);
        }
        {
            float iv = sigmoid_f(a0[3] + (float)xc0[3]);
            float fv = sigmoid_f(a1[3] + (float)xc1[3]);
            float gv = tanh_f  (a2[3] + (float)xc2[3]);
            float ov = sigmoid_f(a3[3] + (float)xc3[3]);
            cr3 = fv * cr3 + iv * gv; hh3 = ov * tanh_f(cr3);
        }
        hp[0] = (_Float16)hh0; hp[1] = (_Float16)hh1;
        hp[2] = (_Float16)hh2; hp[3] = (_Float16)hh3;

        *(f16x4*)(&hb[(step + 1) & 1][col][w * 16 + q * 4]) = hp;
        if (flags & 1)
            *(f16x4*)(h_out + ((size_t)(b0 + col) * TT + step) * 128
                      + w * 16 + q * 4) = hp;
        if ((flags & 2) && step == TT - 1) {
            int ub = w * 16 + q * 4;
            fcred[col][w * 4 + q] =
                hh0 * fc_w[ub] + hh1 * fc_w[ub + 1] +
                hh2 * fc_w[ub + 2] + hh3 * fc_w[ub + 3];
        }
        __syncthreads();   // single barrier per step
        xc0 = xn0; xc1 = xn1; xc2 = xn2; xc3 = xn3;
        xn0 = xf0; xn1 = xf1; xn2 = xf2; xn3 = xf3;
    }

    if ((flags & 2) && tid < 16) {
        float s = fc_b[0];
        #pragma unroll
        for (int j = 0; j < 32; ++j) s += fcred[tid][j];
        out[b0 + tid] = s;
    }
}

extern "C" void kernel_launch(void* const* d_in, const int* in_sizes, int n_in,
                              void* d_out, int out_size, void* d_ws, size_t ws_size,
                              hipStream_t stream) {
    const float* x     = (const float*)d_in[0];
    const float* w_ih0 = (const float*)d_in[1];
    const float* w_hh0 = (const float*)d_in[2];
    const float* b_ih0 = (const float*)d_in[3];
    const float* b_hh0 = (const float*)d_in[4];
    const float* w_ih1 = (const float*)d_in[5];
    const float* w_hh1 = (const float*)d_in[6];
    const float* b_ih1 = (const float*)d_in[7];
    const float* b_hh1 = (const float*)d_in[8];
    const float* fc_w  = (const float*)d_in[9];
    const float* fc_b  = (const float*)d_in[10];
    float* out = (float*)d_out;

    // ws layout (bytes)
    char* ws = (char*)d_ws;
    _Float16* xg     = (_Float16*)(ws);                            // 134217728
    _Float16* h0_all = (_Float16*)(ws + 134217728);                //  33554432
    _Float16* x16    = (_Float16*)(ws + 134217728 + 33554432);     //  16777216
    _Float16* w0_16  = (_Float16*)(ws + 134217728 + 33554432 + 16777216);          // 65536
    _Float16* w1_16  = (_Float16*)(ws + 134217728 + 33554432 + 16777216 + 65536);  // 131072

    cvt_f32_f16<<<dim3(1024), dim3(256), 0, stream>>>(x, x16, (256 * 512 * 64) / 4);
    cvt_f32_f16<<<dim3(32), dim3(256), 0, stream>>>(w_ih0, w0_16, (512 * 64) / 4);
    cvt_f32_f16<<<dim3(64), dim3(256), 0, stream>>>(w_ih1, w1_16, (512 * 128) / 4);

    gemm_xg<<<dim3(MM / 64), dim3(256), 0, stream>>>(x16, w0_16, b_ih0, b_hh0, xg, 64);

    lstm_rec_mfma<<<dim3(16), dim3(512), 0, stream>>>(w_hh0, xg, h0_all,
                                                      fc_w, fc_b, out, 1);

    gemm_xg<<<dim3(MM / 64), dim3(256), 0, stream>>>(h0_all, w1_16, b_ih1, b_hh1, xg, 128);

    lstm_rec_mfma<<<dim3(16), dim3(512), 0, stream>>>(w_hh1, xg, h0_all,
                                                      fc_w, fc_b, out, 2);
}

// Round 9
// 934.571 us; speedup vs baseline: 1.8638x; 1.8638x over previous
//
#include <hip/hip_runtime.h>
#include <hip/hip_fp16.h>

// LSTM B=256,T=512,IN=64,H=128,L=2 + FC:
//  K0 cvt    : x, w_ih0, w_ih1 -> fp16 (ws)
//  KG (MFMA) : xg0 = x16.Wih0^T + bias   [131072,512] fp16 (ws)
//  KR (L0)   : recurrent; writes h0_all fp16
//  KG (MFMA) : xg1 = h0_all.Wih1^T + bias
//  KR (L1)   : recurrent + fused FC -> out
//
// KR round-9 = R4 structure (best measured: 330us/layer) with DRAIN-FREE
// steady-state barriers. __syncthreads lowers to s_waitcnt vmcnt(0) before
// s_barrier, so any in-flight global op at a barrier costs full HBM latency
// (~900 cyc) EVERY step — that was ~800 of R4's 1550 cyc/step. Fix:
//  * xg staged through LDS in 32-step chunks (dbuf 64KB); per-step xg access
//    is a ds_read_u16. Chunk global loads are outstanding at only the first
//    barrier after a boundary -> 1 drain / 32 steps.
//  * h_out buffered in LDS (8KB/chunk), flushed coalesced once per chunk.
// Per-step loop touches ONLY LDS. 2 barriers/step kept (R4's layout is
// activation-optimal: 1 exp/thread, no redundancy — R5/R7 regressions).

#define TT 512
#define MM (256 * 512)

typedef _Float16 f16x2 __attribute__((ext_vector_type(2)));
typedef _Float16 f16x8 __attribute__((ext_vector_type(8)));
typedef float f32x4 __attribute__((ext_vector_type(4)));

#define SH2(v, i) __builtin_shufflevector(v, v, 2*(i), 2*(i)+1)

__device__ __forceinline__ float fdot2_(f16x2 a, f16x2 b, float c) {
    return __builtin_amdgcn_fdot2(a, b, c, false);
}
__device__ __forceinline__ float tanh_f(float x) {
    float e = __expf(2.0f * x);
    return 1.0f - 2.0f * __builtin_amdgcn_rcpf(e + 1.0f);
}

// ---------------- K0: fp32 -> fp16 cvt (vector4) ----------------
__global__ void cvt_f32_f16(const float* __restrict__ src,
                            _Float16* __restrict__ dst, int n4) {
    int i = blockIdx.x * blockDim.x + threadIdx.x;
    int stride = gridDim.x * blockDim.x;
    for (; i < n4; i += stride) {
        float4 v = ((const float4*)src)[i];
        f16x2 a; a.x = (_Float16)v.x; a.y = (_Float16)v.y;
        f16x2 b; b.x = (_Float16)v.z; b.y = (_Float16)v.w;
        ((f16x2*)dst)[2 * i]     = a;
        ((f16x2*)dst)[2 * i + 1] = b;
    }
}

// ---------------- KG: xg[M,512] = A[M,K] . W[512,K]^T + (bih+bhh) ----------
__global__ __launch_bounds__(256, 1) void gemm_xg(
    const _Float16* __restrict__ A, const _Float16* __restrict__ W,
    const float* __restrict__ bih, const float* __restrict__ bhh,
    _Float16* __restrict__ out, int K)
{
    const int l  = threadIdx.x & 63;
    const int w  = threadIdx.x >> 6;
    const int mb = blockIdx.x * 64 + w * 16;
    const int c  = l & 15;
    const int q  = l >> 4;

    __shared__ float biasl[512];
    for (int i = threadIdx.x; i < 512; i += 256) biasl[i] = bih[i] + bhh[i];
    __syncthreads();

    f32x4 C[32];
    #pragma unroll
    for (int i = 0; i < 32; ++i) C[i] = (f32x4){0.f, 0.f, 0.f, 0.f};

    const int nks = K >> 5;
    for (int ks = 0; ks < nks; ++ks) {
        f16x8 Af = *(const f16x8*)(A + (size_t)(mb + c) * K + ks * 32 + q * 8);
        #pragma unroll
        for (int nt = 0; nt < 32; ++nt) {
            f16x8 Bf = *(const f16x8*)(W + (size_t)(nt * 16 + c) * K + ks * 32 + q * 8);
            C[nt] = __builtin_amdgcn_mfma_f32_16x16x32_f16(Af, Bf, C[nt], 0, 0, 0);
        }
    }
    #pragma unroll
    for (int nt = 0; nt < 32; ++nt) {
        float bv = biasl[nt * 16 + c];
        #pragma unroll
        for (int i = 0; i < 4; ++i) {
            int row = mb + q * 4 + i;
            out[(size_t)row * 512 + nt * 16 + c] = (_Float16)(C[nt][i] + bv);
        }
    }
}

// ---------------- KR: one recurrent layer (drain-free steady state) --------
// flags bit0: write h_out (layer0); bit1: final-step FC -> out (layer1)
__global__ __launch_bounds__(512, 2) void lstm_rec(
    const float* __restrict__ whh,      // [512,128] fp32
    const _Float16* __restrict__ xg,    // [B*T,512] fp16 (bias included)
    _Float16* __restrict__ h_out,       // [B*T,128] fp16
    const float* __restrict__ fc_w, const float* __restrict__ fc_b,
    float* __restrict__ out, int flags)
{
    const int t = threadIdx.x;          // gate row 0..511
    const int b = blockIdx.x;
    const int s = t & 1;                // K-half

    __shared__ __align__(16) float4 xgbuf[2][2048];    // 2 x 32KB xg chunks
    __shared__ __align__(16) _Float16 hbuf[2][128];
    __shared__ __align__(16) _Float16 houtb[32 * 128]; // 8KB h chunk
    __shared__ float gacts[512];
    __shared__ float h1f[128];

    // resident weights: rows t and t^1, K-half s => 64 VGPRs total (R4)
    f16x2 w0[32], w1[32];
    {
        const float4* r0 = (const float4*)(whh + t * 128 + s * 64);
        const float4* r1 = (const float4*)(whh + (t ^ 1) * 128 + s * 64);
        #pragma unroll
        for (int k = 0; k < 16; ++k) {
            float4 v = r0[k];
            w0[2 * k].x     = (_Float16)v.x; w0[2 * k].y     = (_Float16)v.y;
            w0[2 * k + 1].x = (_Float16)v.z; w0[2 * k + 1].y = (_Float16)v.w;
            float4 u = r1[k];
            w1[2 * k].x     = (_Float16)u.x; w1[2 * k].y     = (_Float16)u.y;
            w1[2 * k + 1].x = (_Float16)u.z; w1[2 * k + 1].y = (_Float16)u.w;
        }
    }
    if (t < 64) {
        ((f16x2*)hbuf[0])[t] = (f16x2){(_Float16)0.f, (_Float16)0.f};
        ((f16x2*)hbuf[1])[t] = (f16x2){(_Float16)0.f, (_Float16)0.f};
    }

    // ---- xg chunk pipeline: 64B/thread staging regs, 1 chunk ahead ----
    const float4* xsrc = (const float4*)(xg + (size_t)b * TT * 512);
    float4 st0, st1, st2, st3;
    {   // chunk 0 -> LDS buf0
        const float4* p = xsrc + t * 4;
        st0 = p[0]; st1 = p[1]; st2 = p[2]; st3 = p[3];
        float4* d = &xgbuf[0][t * 4];
        d[0] = st0; d[1] = st1; d[2] = st2; d[3] = st3;
    }
    {   // chunk 1 -> regs (held during chunk 0 processing)
        const float4* p = xsrc + 2048 + t * 4;
        st0 = p[0]; st1 = p[1]; st2 = p[2]; st3 = p[3];
    }
    __syncthreads();

    float c = 0.f;
    const f16x8* __restrict__ hva = (const f16x8*)(&hbuf[0][0] + s * 64);
    const f16x8* __restrict__ hvb = (const f16x8*)(&hbuf[1][0] + s * 64);

    int step = 0;
    #pragma unroll 1
    for (int ck = 0; ck < 16; ++ck) {
        const _Float16* xb = (const _Float16*)&xgbuf[ck & 1][0];
        #pragma unroll 2
        for (int i = 0; i < 32; ++i, ++step) {
            const f16x8* __restrict__ hv = (step & 1) ? hvb : hva;
            float a0 = 0.f, a1 = 0.f, p0 = 0.f, p1 = 0.f;
            #pragma unroll
            for (int ch = 0; ch < 8; ++ch) {
                f16x8 h = hv[ch];
                a0 = fdot2_(SH2(h, 0), w0[4 * ch + 0], a0);
                p0 = fdot2_(SH2(h, 0), w1[4 * ch + 0], p0);
                a1 = fdot2_(SH2(h, 1), w0[4 * ch + 1], a1);
                p1 = fdot2_(SH2(h, 1), w1[4 * ch + 1], p1);
                a0 = fdot2_(SH2(h, 2), w0[4 * ch + 2], a0);
                p0 = fdot2_(SH2(h, 2), w1[4 * ch + 2], p0);
                a1 = fdot2_(SH2(h, 3), w0[4 * ch + 3], a1);
                p1 = fdot2_(SH2(h, 3), w1[4 * ch + 3], p1);
            }
            float own   = a0 + a1;                    // P(row t,   half s)
            float other = p0 + p1;                    // P(row t^1, half s)
            float recv  = __shfl_xor(other, 1, 64);   // P(row t,   half s^1)
            float pre   = own + recv + (float)xb[i * 512 + t];

            bool isg = (t >= 256) & (t < 384);        // g-gate -> tanh
            float zz = isg ? 2.f * pre : pre;
            float e  = __expf(-zz);
            float sg = __builtin_amdgcn_rcpf(1.f + e);
            gacts[t] = isg ? 2.f * sg - 1.f : sg;
            __syncthreads();  // B1 (LDS-only in flight)

            if (t < 128) {
                float gi = gacts[t],       gf = gacts[t + 128];
                float gg = gacts[t + 256], go = gacts[t + 384];
                c = gf * c + gi * gg;
                float hh = go * tanh_f(c);
                _Float16 h16 = (_Float16)hh;
                hbuf[(step + 1) & 1][t] = h16;
                houtb[i * 128 + t] = h16;
                if (step == TT - 1) h1f[t] = hh;
            }
            __syncthreads();  // B2 (LDS-only in flight)
        }
        // ---- chunk boundary: flush h chunk, publish next xg chunk ----
        if (flags & 1)
            ((f16x8*)(h_out + ((size_t)b * TT + ck * 32) * 128))[t] =
                ((const f16x8*)houtb)[t];
        if (ck + 1 < 16) {
            float4* d = &xgbuf[(ck + 1) & 1][t * 4];
            d[0] = st0; d[1] = st1; d[2] = st2; d[3] = st3;
        }
        __syncthreads();      // boundary barrier (drains the chunk stores once)
        if (ck + 2 < 16) {
            const float4* p = xsrc + (size_t)(ck + 2) * 2048 + t * 4;
            st0 = p[0]; st1 = p[1]; st2 = p[2]; st3 = p[3];
        }
    }

    if (flags & 2) {
        if (t < 64) {
            float p = h1f[t] * fc_w[t] + h1f[t + 64] * fc_w[t + 64];
            #pragma unroll
            for (int off = 32; off > 0; off >>= 1) p += __shfl_down(p, off, 64);
            if (t == 0) out[b] = p + fc_b[0];
        }
    }
}

extern "C" void kernel_launch(void* const* d_in, const int* in_sizes, int n_in,
                              void* d_out, int out_size, void* d_ws, size_t ws_size,
                              hipStream_t stream) {
    const float* x     = (const float*)d_in[0];
    const float* w_ih0 = (const float*)d_in[1];
    const float* w_hh0 = (const float*)d_in[2];
    const float* b_ih0 = (const float*)d_in[3];
    const float* b_hh0 = (const float*)d_in[4];
    const float* w_ih1 = (const float*)d_in[5];
    const float* w_hh1 = (const float*)d_in[6];
    const float* b_ih1 = (const float*)d_in[7];
    const float* b_hh1 = (const float*)d_in[8];
    const float* fc_w  = (const float*)d_in[9];
    const float* fc_b  = (const float*)d_in[10];
    float* out = (float*)d_out;

    // ws layout (bytes)
    char* ws = (char*)d_ws;
    _Float16* xg     = (_Float16*)(ws);                            // 134217728
    _Float16* h0_all = (_Float16*)(ws + 134217728);                //  33554432
    _Float16* x16    = (_Float16*)(ws + 134217728 + 33554432);     //  16777216
    _Float16* w0_16  = (_Float16*)(ws + 134217728 + 33554432 + 16777216);          // 65536
    _Float16* w1_16  = (_Float16*)(ws + 134217728 + 33554432 + 16777216 + 65536);  // 131072

    cvt_f32_f16<<<dim3(1024), dim3(256), 0, stream>>>(x, x16, (256 * 512 * 64) / 4);
    cvt_f32_f16<<<dim3(32), dim3(256), 0, stream>>>(w_ih0, w0_16, (512 * 64) / 4);
    cvt_f32_f16<<<dim3(64), dim3(256), 0, stream>>>(w_ih1, w1_16, (512 * 128) / 4);

    gemm_xg<<<dim3(MM / 64), dim3(256), 0, stream>>>(x16, w0_16, b_ih0, b_hh0, xg, 64);

    lstm_rec<<<dim3(256), dim3(512), 0, stream>>>(w_hh0, xg, h0_all,
                                                  fc_w, fc_b, out, 1);

    gemm_xg<<<dim3(MM / 64), dim3(256), 0, stream>>>(h0_all, w1_16, b_ih1, b_hh1, xg, 128);

    lstm_rec<<<dim3(256), dim3(512), 0, stream>>>(w_hh1, xg, h0_all,
                                                  fc_w, fc_b, out, 2);
}